// Round 2
// baseline (477.265 us; speedup 1.0000x reference)
//
#include <hip/hip_runtime.h>

#define NV 8192
#define FIN 256
#define FOUT 128
#define SPLITS 8
#define PANEL 1024   // NV / SPLITS

typedef __bf16 bf16_t;
typedef __attribute__((ext_vector_type(8))) __bf16 bf16x8;
typedef __attribute__((ext_vector_type(16))) float f32x16;

// ---------------------------------------------------------------------------
// Kernel 1: Wh = h @ W  (fp32, exact). Stores WhbT (bf16, transposed [F][N]),
// Wh1 = Wh @ a[:128], Wh2 = Wh @ a[128:].  256 blocks x 256 threads.
// ---------------------------------------------------------------------------
__global__ __launch_bounds__(256) void wh_kernel(
    const float* __restrict__ h, const float* __restrict__ W,
    const float* __restrict__ a,
    bf16_t* __restrict__ WhbT, float* __restrict__ Wh1, float* __restrict__ Wh2)
{
  __shared__ float As[64][34];    // [k][i] transposed A tile
  __shared__ float Bs[64][128];   // [k][f]
  __shared__ float Cs[32][129];
  __shared__ float red1[32][16];
  __shared__ float red2[32][16];
  const int t  = threadIdx.x;
  const int i0 = blockIdx.x * 32;
  const int c  = t & 15;   // col group: cols c*8 .. c*8+7
  const int r  = t >> 4;   // row group: rows r*2, r*2+1
  float acc0[8], acc1[8];
  #pragma unroll
  for (int j = 0; j < 8; j++) { acc0[j] = 0.f; acc1[j] = 0.f; }

  for (int k0 = 0; k0 < FIN; k0 += 64) {
    { // stage A (32 rows x 64 k), transposed into LDS
      const int ia = t >> 3;          // 0..31
      const int ka = (t & 7) * 8;     // 0..56
      const float* src = h + (size_t)(i0 + ia) * FIN + k0 + ka;
      float4 v0 = *(const float4*)src;
      float4 v1 = *(const float4*)(src + 4);
      As[ka+0][ia]=v0.x; As[ka+1][ia]=v0.y; As[ka+2][ia]=v0.z; As[ka+3][ia]=v0.w;
      As[ka+4][ia]=v1.x; As[ka+5][ia]=v1.y; As[ka+6][ia]=v1.z; As[ka+7][ia]=v1.w;
    }
    { // stage B (64 k x 128 f)
      const int kb = t >> 2;          // 0..63
      const int cb = (t & 3) * 32;
      const float4* src = (const float4*)(W + (size_t)(k0 + kb) * FOUT + cb);
      float4* dst = (float4*)&Bs[kb][cb];
      #pragma unroll
      for (int q = 0; q < 8; q++) dst[q] = src[q];
    }
    __syncthreads();
    #pragma unroll 4
    for (int k = 0; k < 64; k++) {
      float2 av = *(const float2*)&As[k][r*2];
      float b[8];
      *(float4*)&b[0] = *(const float4*)&Bs[k][c*8];
      *(float4*)&b[4] = *(const float4*)&Bs[k][c*8+4];
      #pragma unroll
      for (int j = 0; j < 8; j++) {
        acc0[j] = fmaf(av.x, b[j], acc0[j]);
        acc1[j] = fmaf(av.y, b[j], acc1[j]);
      }
    }
    __syncthreads();
  }

  // epilogue: Cs tile + per-row dots with a1/a2
  float p1a = 0.f, p2a = 0.f, p1b = 0.f, p2b = 0.f;
  #pragma unroll
  for (int j = 0; j < 8; j++) {
    Cs[r*2][c*8+j]   = acc0[j];
    Cs[r*2+1][c*8+j] = acc1[j];
    float w1 = a[c*8+j];
    float w2 = a[FOUT + c*8+j];
    p1a = fmaf(acc0[j], w1, p1a); p2a = fmaf(acc0[j], w2, p2a);
    p1b = fmaf(acc1[j], w1, p1b); p2b = fmaf(acc1[j], w2, p2b);
  }
  red1[r*2][c]   = p1a; red2[r*2][c]   = p2a;
  red1[r*2+1][c] = p1b; red2[r*2+1][c] = p2b;
  __syncthreads();
  if (t < 32) {
    float s = 0.f;
    #pragma unroll
    for (int q = 0; q < 16; q++) s += red1[t][q];
    Wh1[i0 + t] = s;
  } else if (t < 64) {
    float s = 0.f;
    #pragma unroll
    for (int q = 0; q < 16; q++) s += red2[t-32][q];
    Wh2[i0 + t - 32] = s;
  }
  { // WhbT store: thread -> (f = t&127, i-halves of 16)
    const int f = t & 127, half = t >> 7;
    union { bf16_t b[16]; uint4 v[2]; } pk;
    #pragma unroll
    for (int q = 0; q < 16; q++) pk.b[q] = (bf16_t)Cs[half*16 + q][f];
    uint4* dst = (uint4*)(WhbT + (size_t)f * NV + i0 + half*16);
    dst[0] = pk.v[0]; dst[1] = pk.v[1];
  }
}

// ---------------------------------------------------------------------------
// Kernel 2: fused masked-softmax attention — barrier-free, zero LDS.
// Grid 512 = 64 row-blocks(128 rows) x 8 col-splits; 256 threads (4 waves).
// Each wave owns 32 rows x all 128 out-cols. P is computed directly in MFMA
// A-fragment layout in registers (lane ml,hi -> P[row=ml][k=ks*16+hi*8+j]);
// B-fragments load straight from L2-resident WhbT. adj register-double-
// buffered one chunk (64 cols) ahead.
// ---------------------------------------------------------------------------
#define LOAD8(buf, off) do {                                                  \
    _Pragma("unroll")                                                         \
    for (int ks = 0; ks < 4; ks++) {                                          \
      buf[ks*2]   = *(const int4*)(rowp + (off) + ks*16 + hi8);               \
      buf[ks*2+1] = *(const int4*)(rowp + (off) + ks*16 + hi8 + 4);           \
    } } while (0)

#define PROCESS(buf, jc) do {                                                 \
    const int jbL = j0 + (jc);                                                \
    bf16x8 af[4];                                                             \
    _Pragma("unroll")                                                         \
    for (int ks = 0; ks < 4; ks++) {                                          \
      float4 wA = *(const float4*)(Wh2v + jbL + ks*16 + hi8);                 \
      float4 wB = *(const float4*)(Wh2v + jbL + ks*16 + hi8 + 4);             \
      const float wm[8] = {wA.x,wA.y,wA.z,wA.w, wB.x,wB.y,wB.z,wB.w};         \
      const int4 aa = buf[ks*2], ab = buf[ks*2+1];                            \
      const int am[8] = {aa.x,aa.y,aa.z,aa.w, ab.x,ab.y,ab.z,ab.w};           \
      _Pragma("unroll")                                                       \
      for (int q = 0; q < 8; q++) {                                           \
        float e = wh1 + wm[q];                                                \
        e = fmaxf(e, 0.2f * e);                    /* LeakyReLU(0.2) */       \
        float p = (am[q] > 0) ? __expf(e) : 0.0f;  /* mask + exp */           \
        den_t += p;                                                           \
        af[ks][q] = (bf16_t)p;                                                \
      }                                                                       \
    }                                                                         \
    _Pragma("unroll")                                                         \
    for (int nb = 0; nb < 4; nb++) {                                          \
      _Pragma("unroll")                                                       \
      for (int ks = 0; ks < 4; ks++) {                                        \
        bf16x8 bfv = *(const bf16x8*)(bp + (size_t)(nb*32 + ml) * NV          \
                                      + (jc) + ks*16 + hi8);                  \
        acc[nb] = __builtin_amdgcn_mfma_f32_32x32x16_bf16(af[ks], bfv,        \
                                                          acc[nb], 0, 0, 0); \
      }                                                                       \
    } } while (0)

__global__ __launch_bounds__(256, 2) void attn_kernel(
    const int* __restrict__ adj, const bf16_t* __restrict__ WhbT,
    const float* __restrict__ Wh1v, const float* __restrict__ Wh2v,
    float* __restrict__ nump, float* __restrict__ denp)
{
  const int t     = threadIdx.x;
  const int lane  = t & 63;
  const int w     = t >> 6;        // wave 0..3 -> rows w*32..w*32+31
  const int ml    = lane & 31;
  const int hi    = lane >> 5;
  const int hi8   = hi * 8;
  const int rb    = blockIdx.x >> 3;
  const int split = blockIdx.x & 7;   // == XCD id for L2 locality of WhbT panel
  const int i0    = rb * 128;
  const int j0    = split * PANEL;
  const int row   = i0 + w * 32 + ml;
  const float wh1 = Wh1v[row];
  const int* rowp = adj + (size_t)row * NV + j0;
  const bf16_t* bp = WhbT + j0;
  f32x16 acc[4] = {};
  float den_t = 0.f;
  int4 c0[8], c1[8];

  LOAD8(c0, 0);
  #pragma unroll 1
  for (int jc = 0; jc < PANEL; jc += 128) {
    LOAD8(c1, jc + 64);
    PROCESS(c0, jc);
    const int off2 = (jc + 128 < PANEL) ? jc + 128 : 0;  // harmless re-read on last
    LOAD8(c0, off2);
    PROCESS(c1, jc + 64);
  }

  // den: combine the two k-halves of each row (lanes ml and ml+32)
  den_t += __shfl(den_t, lane ^ 32, 64);
  if (hi == 0) denp[(size_t)split * NV + row] = den_t;

  // num partials; C/D layout: col = lane&31, row = (reg&3)+8*(reg>>2)+4*hi
  float* base = nump + ((size_t)split * NV + i0 + w * 32) * FOUT;
  const int r4 = 4 * hi;
  #pragma unroll
  for (int nb = 0; nb < 4; nb++) {
    #pragma unroll
    for (int reg = 0; reg < 16; reg++) {
      const int crow = (reg & 3) + 8 * (reg >> 2) + r4;
      base[(size_t)crow * FOUT + nb * 32 + ml] = acc[nb][reg];
    }
  }
}

// ---------------------------------------------------------------------------
// Kernel 3: out = elu( (sum_s num_s) / (sum_s den_s) )
// ---------------------------------------------------------------------------
__global__ __launch_bounds__(256) void finalize_kernel(
    const float* __restrict__ nump, const float* __restrict__ denp,
    float* __restrict__ out)
{
  const int gid = blockIdx.x * 256 + threadIdx.x;   // 0 .. 262143
  const int i  = gid >> 5;
  const int f0 = (gid & 31) * 4;
  float den = 0.f;
  #pragma unroll
  for (int s = 0; s < SPLITS; s++) den += denp[(size_t)s * NV + i];
  float4 sv = make_float4(0.f, 0.f, 0.f, 0.f);
  #pragma unroll
  for (int s = 0; s < SPLITS; s++) {
    float4 v = *(const float4*)&nump[((size_t)s * NV + i) * FOUT + f0];
    sv.x += v.x; sv.y += v.y; sv.z += v.z; sv.w += v.w;
  }
  const float inv = 1.0f / den;
  float4 r;
  r.x = sv.x * inv; r.y = sv.y * inv; r.z = sv.z * inv; r.w = sv.w * inv;
  r.x = r.x > 0.f ? r.x : __expf(r.x) - 1.0f;
  r.y = r.y > 0.f ? r.y : __expf(r.y) - 1.0f;
  r.z = r.z > 0.f ? r.z : __expf(r.z) - 1.0f;
  r.w = r.w > 0.f ? r.w : __expf(r.w) - 1.0f;
  *(float4*)&out[(size_t)i * FOUT + f0] = r;
}

// ---------------------------------------------------------------------------
extern "C" void kernel_launch(void* const* d_in, const int* in_sizes, int n_in,
                              void* d_out, int out_size, void* d_ws, size_t ws_size,
                              hipStream_t stream) {
  const float* h  = (const float*)d_in[0];
  const int*  adj = (const int*)d_in[1];
  const float* W  = (const float*)d_in[2];
  const float* a  = (const float*)d_in[3];
  float* out = (float*)d_out;
  char* ws = (char*)d_ws;
  // workspace layout (~36 MB total):
  bf16_t* WhbT = (bf16_t*)ws;                                   // 2 MB
  float* Wh1  = (float*)(ws + 2097152);                         // 32 KB
  float* Wh2  = (float*)(ws + 2097152 + 32768);                 // 32 KB
  float* denp = (float*)(ws + 2097152 + 65536);                 // 256 KB
  float* nump = (float*)(ws + 2097152 + 65536 + 262144);        // 32 MB

  wh_kernel<<<256, 256, 0, stream>>>(h, W, a, WhbT, Wh1, Wh2);
  attn_kernel<<<512, 256, 0, stream>>>(adj, WhbT, Wh1, Wh2, nump, denp);
  finalize_kernel<<<1024, 256, 0, stream>>>(nump, denp, out);
}

// Round 3
// 425.044 us; speedup vs baseline: 1.1229x; 1.1229x over previous
//
#include <hip/hip_runtime.h>

#define NV 8192
#define FIN 256
#define FOUT 128
#define SPLITS 8
#define PANEL 1024   // NV / SPLITS

typedef __bf16 bf16_t;
typedef __attribute__((ext_vector_type(8))) __bf16 bf16x8;
typedef __attribute__((ext_vector_type(4))) float f32x4;

// ---------------------------------------------------------------------------
// Kernel 1: Wh = h @ W (fp32, exact). Stores Wg = Wh in MFMA-B fragment-major
// layout for 16x16x32: element (j, f) at
//   Wg[(j>>5)*4096 + (f>>4)*512 + ((j>>3)&3)*128 + (f&15)*8 + (j&7)]
// so an attn B-load is 64 lanes x 16B fully contiguous.
// Also Wh1 = Wh@a[:128], Wh2 = Wh@a[128:].  256 blocks x 256 threads.
// ---------------------------------------------------------------------------
__global__ __launch_bounds__(256) void wh_kernel(
    const float* __restrict__ h, const float* __restrict__ W,
    const float* __restrict__ a,
    bf16_t* __restrict__ Wg, float* __restrict__ Wh1, float* __restrict__ Wh2)
{
  __shared__ float As[64][34];    // [k][i] transposed A tile
  __shared__ float Bs[64][128];   // [k][f]
  __shared__ float Cs[32][129];
  __shared__ float red1[32][16];
  __shared__ float red2[32][16];
  const int t  = threadIdx.x;
  const int i0 = blockIdx.x * 32;
  const int c  = t & 15;   // col group: cols c*8 .. c*8+7
  const int r  = t >> 4;   // row group: rows r*2, r*2+1
  float acc0[8], acc1[8];
  #pragma unroll
  for (int j = 0; j < 8; j++) { acc0[j] = 0.f; acc1[j] = 0.f; }

  for (int k0 = 0; k0 < FIN; k0 += 64) {
    { // stage A (32 rows x 64 k), transposed into LDS
      const int ia = t >> 3;          // 0..31
      const int ka = (t & 7) * 8;     // 0..56
      const float* src = h + (size_t)(i0 + ia) * FIN + k0 + ka;
      float4 v0 = *(const float4*)src;
      float4 v1 = *(const float4*)(src + 4);
      As[ka+0][ia]=v0.x; As[ka+1][ia]=v0.y; As[ka+2][ia]=v0.z; As[ka+3][ia]=v0.w;
      As[ka+4][ia]=v1.x; As[ka+5][ia]=v1.y; As[ka+6][ia]=v1.z; As[ka+7][ia]=v1.w;
    }
    { // stage B (64 k x 128 f)
      const int kb = t >> 2;          // 0..63
      const int cb = (t & 3) * 32;
      const float4* src = (const float4*)(W + (size_t)(k0 + kb) * FOUT + cb);
      float4* dst = (float4*)&Bs[kb][cb];
      #pragma unroll
      for (int q = 0; q < 8; q++) dst[q] = src[q];
    }
    __syncthreads();
    #pragma unroll 4
    for (int k = 0; k < 64; k++) {
      float2 av = *(const float2*)&As[k][r*2];
      float b[8];
      *(float4*)&b[0] = *(const float4*)&Bs[k][c*8];
      *(float4*)&b[4] = *(const float4*)&Bs[k][c*8+4];
      #pragma unroll
      for (int j = 0; j < 8; j++) {
        acc0[j] = fmaf(av.x, b[j], acc0[j]);
        acc1[j] = fmaf(av.y, b[j], acc1[j]);
      }
    }
    __syncthreads();
  }

  // epilogue: Cs tile + per-row dots with a1/a2
  float p1a = 0.f, p2a = 0.f, p1b = 0.f, p2b = 0.f;
  #pragma unroll
  for (int j = 0; j < 8; j++) {
    Cs[r*2][c*8+j]   = acc0[j];
    Cs[r*2+1][c*8+j] = acc1[j];
    float w1 = a[c*8+j];
    float w2 = a[FOUT + c*8+j];
    p1a = fmaf(acc0[j], w1, p1a); p2a = fmaf(acc0[j], w2, p2a);
    p1b = fmaf(acc1[j], w1, p1b); p2b = fmaf(acc1[j], w2, p2b);
  }
  red1[r*2][c]   = p1a; red2[r*2][c]   = p2a;
  red1[r*2+1][c] = p1b; red2[r*2+1][c] = p2b;
  __syncthreads();
  if (t < 32) {
    float s = 0.f;
    #pragma unroll
    for (int q = 0; q < 16; q++) s += red1[t][q];
    Wh1[i0 + t] = s;
  } else if (t < 64) {
    float s = 0.f;
    #pragma unroll
    for (int q = 0; q < 16; q++) s += red2[t-32][q];
    Wh2[i0 + t - 32] = s;
  }
  { // Wg fragment-major store: thread t handles f = t&127, rows i0+half*16..+15
    const int f = t & 127, half = t >> 7;
    const int fb = f >> 4, f15 = f & 15;
    union { bf16_t b[8]; uint4 v; } p0, p1;
    #pragma unroll
    for (int q = 0; q < 8; q++) {
      p0.b[q] = (bf16_t)Cs[half*16 + q][f];       // kh = 2*half
      p1.b[q] = (bf16_t)Cs[half*16 + 8 + q][f];   // kh = 2*half+1
    }
    size_t base = (size_t)(i0 >> 5) * 4096 + (size_t)fb * 512
                + (size_t)(2*half) * 128 + (size_t)f15 * 8;
    *(uint4*)(Wg + base)       = p0.v;
    *(uint4*)(Wg + base + 128) = p1.v;
  }
}

// ---------------------------------------------------------------------------
// Kernel 2: fused masked-softmax attention. Barrier-free main loop.
// Grid 1024 = 128 row-blocks(64 rows) x 8 col-splits; 256 threads (4 waves),
// wave owns 16 rows x all 128 f (mfma_f32_16x16x32_bf16, acc = 8 x f32x4).
// Per 64-col chunk: P computed in A-fragment layout (lane: m=lane&15,
// k=(lane>>4)*8+q); B-fragments are contiguous 1KB wave loads from Wg.
// Issue order [P, B-loads] | [adj prefetch] | [MFMA] (sched_barriers) keeps
// the adj prefetch in flight across the MFMA's B-wait (in-order vmcnt).
// ---------------------------------------------------------------------------
#define LOADC(buf, jc) do {                                                   \
    buf[0] = *(const int4*)(rowp + (jc));                                     \
    buf[1] = *(const int4*)(rowp + (jc) + 4);                                 \
    buf[2] = *(const int4*)(rowp + (jc) + 32);                                \
    buf[3] = *(const int4*)(rowp + (jc) + 32 + 4);                            \
  } while (0)

#define PCOMP(buf, jc, s, af) do {                                            \
    const int4 aa = buf[(s)*2], ab = buf[(s)*2+1];                            \
    const int am[8] = {aa.x,aa.y,aa.z,aa.w, ab.x,ab.y,ab.z,ab.w};             \
    float4 wA = *(const float4*)&Wh2s[(jc) + (s)*32 + kh8];                   \
    float4 wB = *(const float4*)&Wh2s[(jc) + (s)*32 + kh8 + 4];               \
    const float wm[8] = {wA.x,wA.y,wA.z,wA.w, wB.x,wB.y,wB.z,wB.w};           \
    _Pragma("unroll")                                                         \
    for (int q = 0; q < 8; q++) {                                             \
      float e = wh1 + wm[q];                                                  \
      e = fmaxf(e, 0.2f * e);                     /* LeakyReLU(0.2) */        \
      float p = (am[q] > 0) ? __expf(e) : 0.0f;   /* mask + exp */            \
      den_t += p;                                                             \
      af[q] = (bf16_t)p;                                                      \
    } } while (0)

#define BODY(BUF, JC, NBUF, NJC) do {                                         \
    bf16x8 af0, af1;                                                          \
    PCOMP(BUF, (JC), 0, af0);                                                 \
    PCOMP(BUF, (JC), 1, af1);                                                 \
    const bf16_t* bb0 = Wg + (size_t)((j0 + (JC)) >> 5) * 4096 + lane8;       \
    const bf16_t* bb1 = Wg + (size_t)((j0 + (JC) + 32) >> 5) * 4096 + lane8;  \
    bf16x8 b0[8], b1[8];                                                      \
    _Pragma("unroll")                                                         \
    for (int fb = 0; fb < 8; fb++) {                                          \
      b0[fb] = *(const bf16x8*)(bb0 + fb * 512);                              \
      b1[fb] = *(const bf16x8*)(bb1 + fb * 512);                              \
    }                                                                         \
    __builtin_amdgcn_sched_barrier(0);                                        \
    LOADC(NBUF, (NJC));                                                       \
    __builtin_amdgcn_sched_barrier(0);                                        \
    _Pragma("unroll")                                                         \
    for (int fb = 0; fb < 8; fb++) {                                          \
      acc[fb] = __builtin_amdgcn_mfma_f32_16x16x32_bf16(af0, b0[fb],          \
                                                        acc[fb], 0, 0, 0);    \
      acc[fb] = __builtin_amdgcn_mfma_f32_16x16x32_bf16(af1, b1[fb],          \
                                                        acc[fb], 0, 0, 0);    \
    } } while (0)

__global__ __launch_bounds__(256, 3) void attn_kernel(
    const int* __restrict__ adj, const bf16_t* __restrict__ Wg,
    const float* __restrict__ Wh1v, const float* __restrict__ Wh2v,
    float* __restrict__ nump, float* __restrict__ denp)
{
  __shared__ float Wh2s[PANEL];
  const int t     = threadIdx.x;
  const int lane  = t & 63;
  const int w     = t >> 6;        // wave 0..3 -> rows w*16..w*16+15
  const int f15   = lane & 15;
  const int kh    = lane >> 4;     // 0..3 (k-quarter)
  const int kh8   = kh * 8;
  const int lane8 = lane * 8;
  const int rb    = blockIdx.x >> 3;
  const int split = blockIdx.x & 7;
  const int i0    = rb * 64;
  const int j0    = split * PANEL;
  const int row   = i0 + w * 16 + f15;  // this lane's P row
  const float wh1 = Wh1v[row];
  const int* rowp = adj + (size_t)row * NV + j0 + kh8;

  // stage Wh2 panel (4 KB) into LDS once; broadcast reads, no vmcnt traffic
  *(float4*)&Wh2s[t * 4] = *(const float4*)(Wh2v + j0 + t * 4);
  __syncthreads();

  f32x4 acc[8] = {};
  float den_t = 0.f;
  int4 c0[4], c1[4];

  LOADC(c0, 0);
  #pragma unroll 1
  for (int jc = 0; jc < PANEL; jc += 128) {
    BODY(c0, jc, c1, jc + 64);
    const int njc = (jc + 128 < PANEL) ? jc + 128 : 0;  // harmless re-read at end
    BODY(c1, jc + 64, c0, njc);
  }

  // den: sum the 4 k-quarters of each row (lanes sharing lane&15)
  den_t += __shfl_xor(den_t, 16, 64);
  den_t += __shfl_xor(den_t, 32, 64);
  if (lane < 16) denp[(size_t)split * NV + i0 + w * 16 + lane] = den_t;

  // num partials; C/D layout (16x16): col = lane&15, row = (lane>>4)*4 + reg
  float* base = nump + ((size_t)split * NV + i0 + w * 16) * FOUT;
  #pragma unroll
  for (int fb = 0; fb < 8; fb++) {
    #pragma unroll
    for (int reg = 0; reg < 4; reg++) {
      const int crow = kh * 4 + reg;
      base[(size_t)crow * FOUT + fb * 16 + f15] = acc[fb][reg];
    }
  }
}

// ---------------------------------------------------------------------------
// Kernel 3: out = elu( (sum_s num_s) / (sum_s den_s) )
// ---------------------------------------------------------------------------
__global__ __launch_bounds__(256) void finalize_kernel(
    const float* __restrict__ nump, const float* __restrict__ denp,
    float* __restrict__ out)
{
  const int gid = blockIdx.x * 256 + threadIdx.x;   // 0 .. 262143
  const int i  = gid >> 5;
  const int f0 = (gid & 31) * 4;
  float den = 0.f;
  #pragma unroll
  for (int s = 0; s < SPLITS; s++) den += denp[(size_t)s * NV + i];
  float4 sv = make_float4(0.f, 0.f, 0.f, 0.f);
  #pragma unroll
  for (int s = 0; s < SPLITS; s++) {
    float4 v = *(const float4*)&nump[((size_t)s * NV + i) * FOUT + f0];
    sv.x += v.x; sv.y += v.y; sv.z += v.z; sv.w += v.w;
  }
  const float inv = 1.0f / den;
  float4 r;
  r.x = sv.x * inv; r.y = sv.y * inv; r.z = sv.z * inv; r.w = sv.w * inv;
  r.x = r.x > 0.f ? r.x : __expf(r.x) - 1.0f;
  r.y = r.y > 0.f ? r.y : __expf(r.y) - 1.0f;
  r.z = r.z > 0.f ? r.z : __expf(r.z) - 1.0f;
  r.w = r.w > 0.f ? r.w : __expf(r.w) - 1.0f;
  *(float4*)&out[(size_t)i * FOUT + f0] = r;
}

// ---------------------------------------------------------------------------
extern "C" void kernel_launch(void* const* d_in, const int* in_sizes, int n_in,
                              void* d_out, int out_size, void* d_ws, size_t ws_size,
                              hipStream_t stream) {
  const float* h  = (const float*)d_in[0];
  const int*  adj = (const int*)d_in[1];
  const float* W  = (const float*)d_in[2];
  const float* a  = (const float*)d_in[3];
  float* out = (float*)d_out;
  char* ws = (char*)d_ws;
  // workspace layout (~36 MB total):
  bf16_t* Wg  = (bf16_t*)ws;                                    // 2 MB
  float* Wh1  = (float*)(ws + 2097152);                         // 32 KB
  float* Wh2  = (float*)(ws + 2097152 + 32768);                 // 32 KB
  float* denp = (float*)(ws + 2097152 + 65536);                 // 256 KB
  float* nump = (float*)(ws + 2097152 + 65536 + 262144);        // 32 MB

  wh_kernel<<<256, 256, 0, stream>>>(h, W, a, Wg, Wh1, Wh2);
  attn_kernel<<<1024, 256, 0, stream>>>(adj, Wg, Wh1, Wh2, nump, denp);
  finalize_kernel<<<1024, 256, 0, stream>>>(nump, denp, out);
}